// Round 1
// 959.167 us; speedup vs baseline: 1.0126x; 1.0126x over previous
//
#include <hip/hip_runtime.h>

#define H  64
#define G4 256   // 4*H

typedef float vf4 __attribute__((ext_vector_type(4)));

// fast sigmoid/tanh: v_exp_f32 + v_rcp_f32. Safe at +-inf:
//   x->-inf: exp(-x)=inf -> rcp(inf)=0 ; x->+inf: exp(-x)=0 -> rcp(1)=1
__device__ __forceinline__ float sigm(float x) {
    return __builtin_amdgcn_rcpf(1.0f + __expf(-x));
}
__device__ __forceinline__ float tanh_s(float x) {
    return fmaf(2.0f, sigm(2.0f * x), -1.0f);
}

__device__ __forceinline__ float bcast(float v, int lane) {
    return __int_as_float(__builtin_amdgcn_readlane(__float_as_int(v), lane));
}

// P[v][g] = sum_h table[v][h] * w_ih[g][h] + b_ih[g] + b_hh[g], table[0] = 0
// Forward direction only: the backward LSTM needs exactly one step (token T-1),
// whose gates the lstm_kernel epilogue now computes directly.
__global__ __launch_bounds__(256)
void proj_kernel(const float* __restrict__ emb,
                 const float* __restrict__ w_ih,
                 const float* __restrict__ b_ih,
                 const float* __restrict__ b_hh,
                 float* __restrict__ P,
                 int V)
{
    const int j  = threadIdx.x;       // output gate index 0..255
    const int v0 = blockIdx.x * 8;

    __shared__ float es[8][H];
    // cooperative load of 8 embedding rows (512 floats, 2 per thread)
    {
        int idx = j;
        #pragma unroll
        for (int rep = 0; rep < 2; ++rep, idx += 256) {
            int r = idx >> 6, col = idx & 63;
            int v = v0 + r;
            float val = 0.0f;
            if (v < V && v != 0) val = emb[v * H + col];   // padding_idx=0
            es[r][col] = val;
        }
    }

    vf4 w[16];
    const vf4* w4 = reinterpret_cast<const vf4*>(w_ih + j * H);
    #pragma unroll
    for (int i = 0; i < 16; ++i) w[i] = w4[i];

    float bias = b_ih[j] + b_hh[j];
    __syncthreads();

    #pragma unroll
    for (int r = 0; r < 8; ++r) {
        int v = v0 + r;
        if (v >= V) break;
        float a0 = 0, a1 = 0, a2 = 0, a3 = 0;
        #pragma unroll
        for (int i = 0; i < 16; ++i) {
            a0 = fmaf(es[r][4*i+0], w[i][0], a0);
            a1 = fmaf(es[r][4*i+1], w[i][1], a1);
            a2 = fmaf(es[r][4*i+2], w[i][2], a2);
            a3 = fmaf(es[r][4*i+3], w[i][3], a3);
        }
        P[v * G4 + j] = bias + ((a0 + a1) + (a2 + a3));
    }
}

// One block per batch element. 4 waves; wave w owns gate w (rows 64w..64w+63
// of w_hh). Recurrent weights live in 16 NAMED ext_vector float4 registers,
// pinned with quad-granularity asm: the previous per-element float w[64] pin
// FAILED (rocprof VGPR_Count stayed 40 => 64 floats were never resident, the
// loop re-read 64KB/step from cache). Named vf4s are the verification probe:
// VGPR_Count must rise to ~110.
__global__ __launch_bounds__(256, 1)
void lstm_kernel(const int* __restrict__ x,      // [B,T]
                 const float* __restrict__ Pf,   // [V,4H]
                 const float* __restrict__ w_hh, // [4H,H] (forward)
                 const float* __restrict__ w_ih_b, // [4H,H]
                 const float* __restrict__ b_ih_b, // [4H]
                 const float* __restrict__ b_hh_b, // [4H]
                 const float* __restrict__ emb,  // [V,H]
                 const float* __restrict__ w_fc, // [12,2H]
                 const float* __restrict__ b_fc, // [12]
                 float* __restrict__ out,        // [B,12]
                 int T)
{
    const int b    = blockIdx.x;
    const int j    = threadIdx.x;   // gate-output row 0..255
    const int lane = j & 63;
    const int gate = j >> 6;        // == wave id: 0=i 1=f 2=g 3=o

    // per-thread recurrent weight row: 16 named float4 quads, asm-pinned
    const vf4* w4 = reinterpret_cast<const vf4*>(w_hh + j * H);
    vf4 q0  = w4[0],  q1  = w4[1],  q2  = w4[2],  q3  = w4[3];
    vf4 q4  = w4[4],  q5  = w4[5],  q6  = w4[6],  q7  = w4[7];
    vf4 q8  = w4[8],  q9  = w4[9],  q10 = w4[10], q11 = w4[11];
    vf4 q12 = w4[12], q13 = w4[13], q14 = w4[14], q15 = w4[15];
    asm volatile("" : "+v"(q0),  "+v"(q1),  "+v"(q2),  "+v"(q3));
    asm volatile("" : "+v"(q4),  "+v"(q5),  "+v"(q6),  "+v"(q7));
    asm volatile("" : "+v"(q8),  "+v"(q9),  "+v"(q10), "+v"(q11));
    asm volatile("" : "+v"(q12), "+v"(q13), "+v"(q14), "+v"(q15));

    // branchless activation: act = Aa * sigm(ms*s) + Ba
    const float ms = (gate == 2) ? 2.0f : 1.0f;
    const float Aa = (gate == 2) ? 2.0f : 1.0f;
    const float Ba = (gate == 2) ? -1.0f : 0.0f;

    // transposed gate exchange: g_t[ph][lane] = {i,f,g,o} -> read side is a
    // single contiguous ds_read_b128 (conflict-free) instead of 4 strided b32.
    __shared__ vf4  g_t[2][64];
    __shared__ float hf_s[H];
    __shared__ float hb_s[H];
    __shared__ float e_s[H];

    const int* __restrict__ xrow = x + (long)b * T;

    float h = 0.0f;   // lane's h value (replicated across all 4 waves)
    float c = 0.0f;

    int   tok_next = (T > 1) ? xrow[1] : 0;
    float p_cur    = Pf[xrow[0] * G4 + j];

    float* gslot = reinterpret_cast<float*>(g_t) + (lane * 4 + gate);

    for (int t = 0; t < T; ++t) {
        // prefetch next timestep's projected input (token 0 row as harmless pad)
        float p_next  = Pf[tok_next * G4 + j];
        int tok_next2 = (t + 2 < T) ? xrow[t + 2] : 0;

        // s = p_cur + sum_k w[k] * h[k]   (h broadcast via readlane)
        float a0 = 0, a1 = 0, a2 = 0, a3 = 0;
        #define KSTEP(Q, base) { \
            float h0 = bcast(h, base+0); \
            float h1 = bcast(h, base+1); \
            float h2 = bcast(h, base+2); \
            float h3 = bcast(h, base+3); \
            a0 = fmaf(Q[0], h0, a0); \
            a1 = fmaf(Q[1], h1, a1); \
            a2 = fmaf(Q[2], h2, a2); \
            a3 = fmaf(Q[3], h3, a3); }
        KSTEP(q0,   0) KSTEP(q1,   4) KSTEP(q2,   8) KSTEP(q3,  12)
        KSTEP(q4,  16) KSTEP(q5,  20) KSTEP(q6,  24) KSTEP(q7,  28)
        KSTEP(q8,  32) KSTEP(q9,  36) KSTEP(q10, 40) KSTEP(q11, 44)
        KSTEP(q12, 48) KSTEP(q13, 52) KSTEP(q14, 56) KSTEP(q15, 60)
        #undef KSTEP

        float s   = p_cur + ((a0 + a1) + (a2 + a3));
        float act = fmaf(Aa, sigm(ms * s), Ba);

        const int ph = t & 1;
        gslot[ph << 8] = act;                  // ds_write_b32, transposed slot
        // lgkmcnt-only barrier: LDS write visible to the CU, but the Pf
        // prefetch (vmcnt) stays in flight across the barrier (unlike
        // __syncthreads(), which drains vmcnt(0) too).
        asm volatile("s_waitcnt lgkmcnt(0)" ::: "memory");
        __builtin_amdgcn_s_barrier();

        vf4 gv = g_t[ph][lane];                // one ds_read_b128: {i,f,g,o}
        c = fmaf(gv[1], c, gv[0] * gv[2]);
        h = gv[3] * tanh_s(c);

        p_cur    = p_next;
        tok_next = tok_next2;
    }

    // ---- epilogue ----
    // backward LSTM = exactly one step (hs_b[0]) with zero initial state, so
    // its gates are just w_ih_b . emb[last_token] + biases, computed here
    // directly (Pb precompute eliminated).
    int tokL = xrow[T - 1];
    if (gate == 0) hf_s[lane] = h;
    if (j < H) e_s[j] = (tokL != 0) ? emb[tokL * H + j] : 0.0f;  // padding_idx=0
    __syncthreads();   // also protects g_t reuse below (all waves past loop)

    float accb = 0.0f;
    {
        const vf4* wb4 = reinterpret_cast<const vf4*>(w_ih_b + j * H);
        #pragma unroll
        for (int i = 0; i < 16; ++i) {
            vf4 wq = wb4[i];
            accb = fmaf(wq[0], e_s[4*i+0], accb);
            accb = fmaf(wq[1], e_s[4*i+1], accb);
            accb = fmaf(wq[2], e_s[4*i+2], accb);
            accb = fmaf(wq[3], e_s[4*i+3], accb);
        }
    }
    float gb = accb + b_ih_b[j] + b_hh_b[j];
    gslot[0] = fmaf(Aa, sigm(ms * gb), Ba);    // reuse buffer 0 of g_t
    __syncthreads();

    if (j < H) {
        vf4 gv = g_t[0][j];
        float cb = gv[0] * gv[2];              // f*c0 = 0
        hb_s[j] = gv[3] * tanh_s(cb);
    }
    __syncthreads();

    // final FC: y[b, j] = b_fc[j] + [h_f | h_b] . w_fc[j]
    if (j < 12) {
        float acc = b_fc[j];
        const float* wf = w_fc + j * (2 * H);
        #pragma unroll
        for (int k = 0; k < H; ++k) acc = fmaf(hf_s[k], wf[k], acc);
        #pragma unroll
        for (int k = 0; k < H; ++k) acc = fmaf(hb_s[k], wf[H + k], acc);
        out[b * 12 + j] = acc;
    }
}

extern "C" void kernel_launch(void* const* d_in, const int* in_sizes, int n_in,
                              void* d_out, int out_size, void* d_ws, size_t ws_size,
                              hipStream_t stream)
{
    const int*   x      = (const int*)  d_in[0];
    const float* emb    = (const float*)d_in[1];
    const float* w_ih_f = (const float*)d_in[2];
    const float* w_hh_f = (const float*)d_in[3];
    const float* b_ih_f = (const float*)d_in[4];
    const float* b_hh_f = (const float*)d_in[5];
    const float* w_ih_b = (const float*)d_in[6];
    // d_in[7] = w_hh_b (unused: backward runs exactly one step from zero state)
    const float* b_ih_b = (const float*)d_in[8];
    const float* b_hh_b = (const float*)d_in[9];
    const float* w_fc   = (const float*)d_in[10];
    const float* b_fc   = (const float*)d_in[11];
    float* out = (float*)d_out;

    const int B = out_size / 12;
    const int T = in_sizes[0] / B;
    const int V = in_sizes[1] / H;

    float* Pf = (float*)d_ws;                   // [V,4H] (2 MB)

    int pblocks = (V + 7) / 8;
    proj_kernel<<<pblocks, 256, 0, stream>>>(emb, w_ih_f, b_ih_f, b_hh_f, Pf, V);
    lstm_kernel<<<B, 256, 0, stream>>>(x, Pf, w_hh_f, w_ih_b, b_ih_b, b_hh_b,
                                       emb, w_fc, b_fc, out, T);
}